// Round 8
// baseline (28.996 us; speedup 1.0000x reference)
//
#include <hip/hip_runtime.h>

// ---------------- problem constants ----------------
#define DTSTEP  3600.0
#define T_STEPS 1048576
#define LCH     8                     // u-rows per chunk (one chunk per thread)
#define TPB     512                   // threads per block (8 waves)
#define NBLK    256                   // block = 4096 steps; 256 blocks <= 256 CUs (co-resident)
#define MAGIC   0x51CAFE17u

// sPW[r] = M^(2^(r+3)), r=0..16  (k=3..19):
//   r=0..5  : intra-wave scan (d=2^r chunks of 8 steps)  + per-lane offset M^(8l)
//   r=6..8  : cross-wave scan (d=2^r waves of 512 steps) + per-wave offset M^(512w)
//   r=9..16 : cross-block weights M^(4096*2^r)
// ws: aggregates float[256*3] at 0; flags uint[256] at float-offset 1024.

__device__ inline void matsq3(double* C){
  double R[9];
#pragma unroll
  for (int r=0;r<3;r++){
#pragma unroll
    for (int c=0;c<3;c++){
      R[r*3+c] = C[r*3+0]*C[0+c] + C[r*3+1]*C[3+c] + C[r*3+2]*C[6+c];
    }
  }
#pragma unroll
  for (int k=0;k<9;k++) C[k]=R[k];
}

// thread-0-per-block: build M,N (f32) + 17 matrix powers via f64 squaring
__device__ void setup_from_rc(const float* __restrict__ rc,
                              float* __restrict__ sMN, float* __restrict__ sPW){
  const float Rg = rc[0]*10.f+1.f, Ri = rc[1]*10.f+1.f, Re = rc[2]*10.f+1.f, Rw = rc[3]*10.f+1.f;
  const float Cai = rc[4]*1e6f+1e5f, Cwe = rc[5]*1e6f+1e5f, Cwi = rc[6]*1e6f+1e5f;
  double Md[9];
  Md[0] = 1.0 + DTSTEP*(-(1.0/Rg + 1.0/Ri)/Cai);
  Md[1] = 0.0;
  Md[2] = DTSTEP*(1.0/((double)Ri*(double)Cai));
  Md[3] = 0.0;
  Md[4] = 1.0 + DTSTEP*(-(1.0/Re + 1.0/Rw)/Cwe);
  Md[5] = DTSTEP*(1.0/((double)Rw*(double)Cwe));
  Md[6] = DTSTEP*(1.0/((double)Ri*(double)Cwi));
  Md[7] = DTSTEP*(1.0/((double)Rw*(double)Cwi));
  Md[8] = 1.0 + DTSTEP*(-(1.0/Rw + 1.0/Ri)/Cwi);
  sMN[0]=(float)Md[0]; sMN[1]=(float)Md[2]; sMN[2]=(float)Md[4]; sMN[3]=(float)Md[5];
  sMN[4]=(float)Md[6]; sMN[5]=(float)Md[7]; sMN[6]=(float)Md[8];
  sMN[7] =(float)(DTSTEP*(1.0/((double)Rg*(double)Cai)));   // N0
  sMN[8] =(float)(DTSTEP*(1.0/(double)Cai));                // N1
  sMN[9] =(float)(DTSTEP*(1.0/(double)Cai));                // N2
  sMN[10]=(float)(DTSTEP*(1.0/((double)Re*(double)Cwe)));   // N5
  sMN[11]=(float)(DTSTEP*(1.0/(double)Cwe));                // N8
  sMN[12]=(float)(DTSTEP*(1.0/(double)Cwi));                // N14
  double C[9];
#pragma unroll
  for (int k=0;k<9;k++) C[k]=Md[k];
  for (int k=1;k<=19;k++){
    matsq3(C);                                   // C = M^(2^k)
    if (k>=3){
#pragma unroll
      for (int j=0;j<9;j++) sPW[(k-3)*9+j] = (float)C[j];
    }
  }
}

struct MN { float M0,M2,M4,M5,M6,M7,M8, N0,N1,N2,N5,N8,N14; };

__device__ inline MN mn_from_lds(const float* __restrict__ sMN){
  MN p;
  p.M0=sMN[0]; p.M2=sMN[1]; p.M4=sMN[2]; p.M5=sMN[3];
  p.M6=sMN[4]; p.M7=sMN[5]; p.M8=sMN[6];
  p.N0=sMN[7]; p.N1=sMN[8]; p.N2=sMN[9];
  p.N5=sMN[10]; p.N8=sMN[11]; p.N14=sMN[12];
  return p;
}

// v <- M v + N u_j over the chunk (exploits exact zeros in M,N)
__device__ inline void chunk_v(const float* uu, const MN& mn, float& v0, float& v1, float& v2){
  v0=0.f; v1=0.f; v2=0.f;
#pragma unroll
  for (int j=0;j<LCH;j++){
    const float u0=uu[j*5+0],u1=uu[j*5+1],u2=uu[j*5+2],u3=uu[j*5+3],u4v=uu[j*5+4];
    const float c0 = fmaf(mn.N0,u0, fmaf(mn.N1,u1, mn.N2*u2));
    const float c1 = fmaf(mn.N5,u0, mn.N8*u3);
    const float c2 = mn.N14*u4v;
    const float n0 = fmaf(mn.M0,v0, fmaf(mn.M2,v2, c0));
    const float n1 = fmaf(mn.M4,v1, fmaf(mn.M5,v2, c1));
    const float n2 = fmaf(mn.M6,v0, fmaf(mn.M7,v1, fmaf(mn.M8,v2, c2)));
    v0=n0; v1=n1; v2=n2;
  }
}

// x <- M^(2^(BASE+3) * e) x via bit-decomposed applies (powers of M commute)
template<int BASE, int NBITS>
__device__ inline void apply_pw(const float* __restrict__ sPW, unsigned e,
                                float& x0, float& x1, float& x2){
#pragma unroll
  for (int r=0;r<NBITS;r++){
    if (e & (1u<<r)){
      const float* Q = &sPW[(BASE+r)*9];
      const float y0 = fmaf(Q[0],x0, fmaf(Q[1],x1, Q[2]*x2));
      const float y1 = fmaf(Q[3],x0, fmaf(Q[4],x1, Q[5]*x2));
      const float y2 = fmaf(Q[6],x0, fmaf(Q[7],x1, Q[8]*x2));
      x0=y0; x1=y1; x2=y2;
    }
  }
}

__global__ __launch_bounds__(TPB) void k_fused(const float* __restrict__ u,
                                               const float* __restrict__ rc,
                                               const float* __restrict__ x_init,
                                               float* __restrict__ wsAgg,
                                               unsigned int* __restrict__ wsFlag,
                                               float* __restrict__ out){
  __shared__ float sMN[13];
  __shared__ float sPW[17*9];
  __shared__ float wagg[8][3];      // per-wave aggregates
  __shared__ float woff[8][3];      // inclusive cross-wave scan
  __shared__ float partial[8][3];   // S-reduction partials
  const int tid  = threadIdx.x;
  const int blk  = blockIdx.x;
  const int lane = tid & 63;
  const int wid  = tid >> 6;
  const int i    = blk*TPB + tid;                // chunk id
  // u loads issued first (DRAM fetch overlaps setup)
  float uu[LCH*5];
  const float4* u4 = reinterpret_cast<const float4*>(u) + (size_t)i*(LCH*5/4);
#pragma unroll
  for (int k=0;k<LCH*5/4;k++){
    const float4 q = u4[k];
    uu[k*4+0]=q.x; uu[k*4+1]=q.y; uu[k*4+2]=q.z; uu[k*4+3]=q.w;
  }
  if (tid==0) setup_from_rc(rc, sMN, sPW);
  __syncthreads();                                                  // B1
  const MN mn = mn_from_lds(sMN);
  float L0,L1,L2;
  chunk_v(uu, mn, L0,L1,L2);
  // ---- barrier-free intra-wave inclusive affine scan (6 shfl rounds) ----
#pragma unroll
  for (int r=0;r<6;r++){
    const int d = 1<<r;
    const float* Q = &sPW[r*9];
    const float p0=__shfl_up(L0,(unsigned)d,64);
    const float p1=__shfl_up(L1,(unsigned)d,64);
    const float p2=__shfl_up(L2,(unsigned)d,64);
    if (lane >= d){
      const float y0 = fmaf(Q[0],p0, fmaf(Q[1],p1, fmaf(Q[2],p2, L0)));
      const float y1 = fmaf(Q[3],p0, fmaf(Q[4],p1, fmaf(Q[5],p2, L1)));
      const float y2 = fmaf(Q[6],p0, fmaf(Q[7],p1, fmaf(Q[8],p2, L2)));
      L0=y0; L1=y1; L2=y2;
    }
  }
  if (lane==63){ wagg[wid][0]=L0; wagg[wid][1]=L1; wagg[wid][2]=L2; }
  __syncthreads();                                                  // B2
  // ---- cross-wave scan over 8 aggregates (wave 0, 3 shfl rounds); publish early ----
  if (wid==0){
    float a0=0.f,a1=0.f,a2=0.f;
    if (lane<8){ a0=wagg[lane][0]; a1=wagg[lane][1]; a2=wagg[lane][2]; }
#pragma unroll
    for (int r=0;r<3;r++){
      const int d = 1<<r;
      const float* Q = &sPW[(6+r)*9];
      const float p0=__shfl_up(a0,(unsigned)d,64);
      const float p1=__shfl_up(a1,(unsigned)d,64);
      const float p2=__shfl_up(a2,(unsigned)d,64);
      if (lane>=d && lane<8){
        const float y0 = fmaf(Q[0],p0, fmaf(Q[1],p1, fmaf(Q[2],p2, a0)));
        const float y1 = fmaf(Q[3],p0, fmaf(Q[4],p1, fmaf(Q[5],p2, a1)));
        const float y2 = fmaf(Q[6],p0, fmaf(Q[7],p1, fmaf(Q[8],p2, a2)));
        a0=y0; a1=y1; a2=y2;
      }
    }
    if (lane==7){                                 // block aggregate -> publish NOW
      __hip_atomic_store(&wsAgg[blk*3+0], a0, __ATOMIC_RELAXED, __HIP_MEMORY_SCOPE_AGENT);
      __hip_atomic_store(&wsAgg[blk*3+1], a1, __ATOMIC_RELAXED, __HIP_MEMORY_SCOPE_AGENT);
      __hip_atomic_store(&wsAgg[blk*3+2], a2, __ATOMIC_RELAXED, __HIP_MEMORY_SCOPE_AGENT);
      __hip_atomic_store(&wsFlag[blk], MAGIC, __ATOMIC_RELEASE, __HIP_MEMORY_SCOPE_AGENT);
    }
    if (lane<8){ woff[lane][0]=a0; woff[lane][1]=a1; woff[lane][2]=a2; }
  }
  __syncthreads();                                                  // B3
  // ---- block start S = M^(4096*blk) x_init + sum_{j<blk} M^(4096*(blk-1-j)) agg_j ----
  float c0=0.f, c1=0.f, c2=0.f;
  if (tid < blk){
    while (__hip_atomic_load(&wsFlag[tid], __ATOMIC_RELAXED, __HIP_MEMORY_SCOPE_AGENT) != MAGIC)
      __builtin_amdgcn_s_sleep(2);
    (void)__hip_atomic_load(&wsFlag[tid], __ATOMIC_ACQUIRE, __HIP_MEMORY_SCOPE_AGENT);
    c0=__hip_atomic_load(&wsAgg[tid*3+0], __ATOMIC_RELAXED, __HIP_MEMORY_SCOPE_AGENT);
    c1=__hip_atomic_load(&wsAgg[tid*3+1], __ATOMIC_RELAXED, __HIP_MEMORY_SCOPE_AGENT);
    c2=__hip_atomic_load(&wsAgg[tid*3+2], __ATOMIC_RELAXED, __HIP_MEMORY_SCOPE_AGENT);
    apply_pw<9,8>(sPW, (unsigned)(blk-1-tid), c0,c1,c2);
  } else if (tid==TPB-1){
    c0=x_init[0]; c1=x_init[1]; c2=x_init[2];
    apply_pw<9,8>(sPW, (unsigned)blk, c0,c1,c2);
  }
#pragma unroll
  for (int off=32; off>0; off>>=1){
    c0 += __shfl_down(c0, (unsigned)off, 64);
    c1 += __shfl_down(c1, (unsigned)off, 64);
    c2 += __shfl_down(c2, (unsigned)off, 64);
  }
  if (lane==0){ partial[wid][0]=c0; partial[wid][1]=c1; partial[wid][2]=c2; }
  __syncthreads();                                                  // B4
  float S0=0.f,S1=0.f,S2=0.f;
#pragma unroll
  for (int w=0;w<8;w++){ S0+=partial[w][0]; S1+=partial[w][1]; S2+=partial[w][2]; }
  // ---- chunk start: x = M^(8*lane) * (M^(512*wid) S + W_{wid-1}) + L_{tid-1} ----
  float x0=S0, x1=S1, x2=S2;
  apply_pw<6,3>(sPW, (unsigned)wid, x0,x1,x2);
  if (wid>0){ x0+=woff[wid-1][0]; x1+=woff[wid-1][1]; x2+=woff[wid-1][2]; }
  apply_pw<0,6>(sPW, (unsigned)lane, x0,x1,x2);
  {
    const float q0=__shfl_up(L0,1u,64);
    const float q1=__shfl_up(L1,1u,64);
    const float q2=__shfl_up(L2,1u,64);
    if (lane>0){ x0+=q0; x1+=q1; x2+=q2; }
  }
  // ---- replay 8 steps, write f32 outputs ----
  float px[LCH*3], py[LCH];
#pragma unroll
  for (int j=0;j<LCH;j++){
    py[j]=x0;                                    // y_t = C x_t (pre-update)
    const float u0=uu[j*5+0],u1=uu[j*5+1],u2=uu[j*5+2],u3=uu[j*5+3],u4v=uu[j*5+4];
    const float d0 = fmaf(mn.N0,u0, fmaf(mn.N1,u1, mn.N2*u2));
    const float d1 = fmaf(mn.N5,u0, mn.N8*u3);
    const float d2 = mn.N14*u4v;
    const float n0 = fmaf(mn.M0,x0, fmaf(mn.M2,x2, d0));
    const float n1 = fmaf(mn.M4,x1, fmaf(mn.M5,x2, d1));
    const float n2 = fmaf(mn.M6,x0, fmaf(mn.M7,x1, fmaf(mn.M8,x2, d2)));
    x0=n0; x1=n1; x2=n2;
    px[j*3+0]=x0; px[j*3+1]=x1; px[j*3+2]=x2;    // xsol_t = x_{t+1}
  }
  float4* xo4 = reinterpret_cast<float4*>(out) + (size_t)i*6;
#pragma unroll
  for (int m=0;m<6;m++)
    xo4[m] = make_float4(px[4*m+0],px[4*m+1],px[4*m+2],px[4*m+3]);
  float4* yo4 = reinterpret_cast<float4*>(out) + (size_t)(3*T_STEPS/4) + (size_t)i*2;
  yo4[0] = make_float4(py[0],py[1],py[2],py[3]);
  yo4[1] = make_float4(py[4],py[5],py[6],py[7]);
}

extern "C" void kernel_launch(void* const* d_in, const int* in_sizes, int n_in,
                              void* d_out, int out_size, void* d_ws, size_t ws_size,
                              hipStream_t stream) {
  (void)out_size; (void)ws_size;
  const float* x_init = (const float*)d_in[0];
  const float* u      = (const float*)d_in[1];
  const float* rc     = (const float*)d_in[2];
  for (int k=0;k<n_in;k++){
    if (in_sizes[k]==3) x_init = (const float*)d_in[k];
    else if (in_sizes[k]==7) rc = (const float*)d_in[k];
    else if (in_sizes[k]==T_STEPS*5) u = (const float*)d_in[k];
  }
  float* wsAgg = (float*)d_ws;                                  // 256*3 floats
  unsigned int* wsFlag = (unsigned int*)((float*)d_ws + 1024);  // 256 flags
  float* out = (float*)d_out;

  k_fused<<<NBLK, TPB, 0, stream>>>(u, rc, x_init, wsAgg, wsFlag, out);
}